// Round 4
// baseline (99.481 us; speedup 1.0000x reference)
//
#include <hip/hip_runtime.h>
#include <cmath>

#define IMG_W 1024
#define RROWS 8             // output rows per wave-band
#define STEPS (RROWS + 6)   // source rows swept (6-row pipeline warmup)
#define OCW   58            // output cols per wave (64 lanes - 6 halo)

// separable Gaussian: w(ky,kx) = gv[ky]*gh[kx], 1/(8*pi) folded into gv
struct GK { float gh[7]; float gv[7]; };

// One wave per block: no __syncthreads anywhere. LDS exchange is
// wave-synchronous (the LDS pipe executes one wave's ops in order);
// wave_barrier() only prevents compiler reordering.
__global__ __launch_bounds__(64)
void mind_wave(const float* __restrict__ img1, const float* __restrict__ img2,
               float* __restrict__ out, GK gk)
{
    __shared__ float4 buf[72];          // one row of pointwise fields (H,V,D,U)

    const int lane = (int)threadIdx.x;                 // 0..63 == column owner
    const int X0 = 4 + OCW * (int)blockIdx.x;          // first source col (block-uniform)
    const int Y0 = 7 + RROWS * (int)blockIdx.y;        // first output row (block-uniform)

    const int sxr = X0 + lane;                         // this lane's source col (raw)
    const int sx  = min(sxr, 1023);                    // clamp only affects masked lanes
    const int sxp = sx ^ 512;                          // the only in-bounds x-shift source
    const bool xok = (lane >= 3) && (lane <= 60) && (sxr <= 1016);

    // fold the x-mask into per-lane premasked weights (zero mask VALU in-loop):
    // tap kx of this lane's h-conv touches source col sxr + kx - 3
    float glx[7], ghx[7];
    #pragma unroll
    for (int kx = 0; kx < 7; ++kx) {
        const bool lo = (((sxr + kx - 3) & 512) == 0); // col<512 -> shift +1 valid
        glx[kx] = lo ? gk.gh[kx] : 0.f;
        ghx[kx] = lo ? 0.f : gk.gh[kx];
    }

    // 7-deep sliding windows of the 6 horizontally-convolved fields
    float wHlo[7] = {0}, wHhi[7] = {0}, wV[7] = {0},
          wDlo[7] = {0}, wDhi[7] = {0}, wU[7] = {0};
    float tsum = 0.f;

    #pragma unroll
    for (int s = 0; s < STEPS; ++s) {
        // ---- pointwise fields for source row Y0-3+s ----
        const int sr  = min(Y0 - 3 + s, 1023);   // clamp only affects masked rows
        const int srp = sr ^ 512;                // the only in-bounds y-shift source
        const float* __restrict__ r2  = img2 + sr  * IMG_W;   // SGPR row bases
        const float* __restrict__ r2p = img2 + srp * IMG_W;
        const float* __restrict__ r1  = img1 + sr  * IMG_W;
        const float* __restrict__ r1p = img1 + srp * IMG_W;
        const float a = r2[sx], b = r2[sxp], c = r2p[sx], d = r2p[sxp];
        const float u = r1[sx], ub = r1[sxp], uc = r1p[sx];
        const float a2 = a * a;
        const float tb = a - b, tc = a - c, td = a - d;
        const float su = u - ub, sv = u - uc;
        float4 f;
        f.x = fmaf(tb, tb, -a2);                      // H: (a-b)^2 - a^2
        f.y = fmaf(tc, tc, -a2);                      // V
        f.z = fmaf(td, td, -a2);                      // D
        f.w = fmaf(u, u + u, fmaf(su, su, sv * sv));  // U: 4*Vimg integrand
        buf[lane + 3] = f;
        __builtin_amdgcn_wave_barrier();   // keep write before the reads below

        // ---- horizontal 7-tap conv (lanes 3..60 valid; edges garbage->masked) ----
        float hHlo = 0, hHhi = 0, hV = 0, hDlo = 0, hDhi = 0, hU = 0;
        #pragma unroll
        for (int kx = 0; kx < 7; ++kx) {
            const float4 g = buf[lane + kx];
            hHlo = fmaf(glx[kx],   g.x, hHlo);
            hHhi = fmaf(ghx[kx],   g.x, hHhi);
            hV   = fmaf(gk.gh[kx], g.y, hV);
            hDlo = fmaf(glx[kx],   g.z, hDlo);
            hDhi = fmaf(ghx[kx],   g.z, hDhi);
            hU   = fmaf(gk.gh[kx], g.w, hU);
        }
        __builtin_amdgcn_wave_barrier();   // keep reads before next step's write

        // push into windows (full unroll -> register renames, no moves)
        #pragma unroll
        for (int i = 0; i < 6; ++i) {
            wHlo[i] = wHlo[i+1]; wHhi[i] = wHhi[i+1]; wV[i] = wV[i+1];
            wDlo[i] = wDlo[i+1]; wDhi[i] = wDhi[i+1]; wU[i] = wU[i+1];
        }
        wHlo[6] = hHlo; wHhi[6] = hHhi; wV[6] = hV;
        wDlo[6] = hDlo; wDhi[6] = hDhi; wU[6] = hU;

        // ---- vertical conv + epilogue for output row y = Y0 + s - 6 ----
        if (s >= 6) {
            const int y = Y0 + s - 6;
            if (y <= 1017) {                 // block-uniform gate
                float Ph=0,Qh=0,Pv=0,Qv=0,Ppp=0,Ppm=0,Pmp=0,Pmm=0,V4=0;
                #pragma unroll
                for (int ky = 0; ky < 7; ++ky) {
                    const float g = gk.gv[ky];
                    const bool ylo = (((y - 3 + ky) & 512) == 0);  // uniform
                    const float wl = ylo ? g : 0.f;
                    const float wh = ylo ? 0.f : g;
                    Ph  = fmaf(g,  wHlo[ky], Ph);
                    Qh  = fmaf(g,  wHhi[ky], Qh);
                    Pv  = fmaf(wl, wV[ky],   Pv);
                    Qv  = fmaf(wh, wV[ky],   Qv);
                    Ppp = fmaf(wl, wDlo[ky], Ppp);
                    Ppm = fmaf(wh, wDlo[ky], Ppm);
                    Pmp = fmaf(wl, wDhi[ky], Pmp);
                    Pmm = fmaf(wh, wDhi[ky], Pmm);
                    V4  = fmaf(g,  wU[ky],   V4);
                }
                const float V = fmaf(V4, 0.25f, 1e-5f);
                const float invV = 1.0f / V;
                float M = fminf(0.f, Ph);
                M = fminf(M, Qh);  M = fminf(M, Pv);  M = fminf(M, Qv);
                M = fminf(M, Ppp); M = fminf(M, Pmp); M = fminf(M, Ppm); M = fminf(M, Pmm);
                // sum over 80 shifts of exp(-(D_s - Dmin)/V); 72 far shifts share D=T0
                const float pix = 72.f * __expf(M * invV)
                    + __expf((M - Ph ) * invV) + __expf((M - Qh ) * invV)
                    + __expf((M - Pv ) * invV) + __expf((M - Qv ) * invV)
                    + __expf((M - Ppp) * invV) + __expf((M - Pmp) * invV)
                    + __expf((M - Ppm) * invV) + __expf((M - Pmm) * invV);
                tsum += xok ? pix : 0.f;     // cndmask kills masked lanes' garbage/NaN
            }
        }
    }

    // ---- wave reduction + one atomic per wave ----
    #pragma unroll
    for (int off = 32; off > 0; off >>= 1)
        tsum += __shfl_down(tsum, off, 64);
    if (lane == 0)
        atomicAdd(out, tsum * (1.0f / 81688800.0f));   // 80 * 1011 * 1010
}

extern "C" void kernel_launch(void* const* d_in, const int* in_sizes, int n_in,
                              void* d_out, int out_size, void* d_ws, size_t ws_size,
                              hipStream_t stream) {
    const float* img1 = (const float*)d_in[0];
    const float* img2 = (const float*)d_in[1];
    float* out = (float*)d_out;

    GK gk;
    for (int i = 0; i < 7; ++i) {
        const double d = i - 3;
        gk.gh[i] = (float)std::exp(-(d * d) / 8.0);
        gk.gv[i] = (float)(std::exp(-(d * d) / 8.0) / (8.0 * M_PI));
    }

    hipMemsetAsync(d_out, 0, sizeof(float), stream);
    dim3 block(64, 1);
    dim3 grid(18, 127);  // 18*58=1044 >= 1010 cols ; 127*8=1016 >= 1011 rows
    mind_wave<<<grid, block, 0, stream>>>(img1, img2, out, gk);
}